// Round 15
// baseline (263.250 us; speedup 1.0000x reference)
//
#include <hip/hip_runtime.h>
#include <math.h>

#define BATCH   8
#define CCH     512
#define NHEADS  8
#define HD      64
#define NGROUPS 32
#define CPG     16
#define NSP     4096      // H*W
#define O1      1536      // 3*C

typedef __attribute__((ext_vector_type(8))) short          short8;
typedef __attribute__((ext_vector_type(8))) unsigned short ushort8;
typedef __attribute__((ext_vector_type(4))) unsigned short ushort4v;
typedef __attribute__((ext_vector_type(4))) float          float4v;

#define GLOAD_LDS16(g, s) __builtin_amdgcn_global_load_lds(                   \
    (const __attribute__((address_space(1))) void*)(g),                       \
    (__attribute__((address_space(3))) void*)(s), 16, 0, 0)

// ---------------------------------------------------------------------------
__device__ __forceinline__ float phi_act(float v) {   // elu(x)+1
    return v > 0.f ? v + 1.f : __expf(v);
}
__device__ __forceinline__ unsigned short f2bf(float f) {  // RNE fp32->bf16
    union { float f; unsigned int u; } c; c.f = f;
    unsigned int u = c.u;
    u += 0x7fffu + ((u >> 16) & 1u);
    return (unsigned short)(u >> 16);
}
__device__ __forceinline__ float bf2f(unsigned short s) {
    union { unsigned int u; float f; } c; c.u = ((unsigned int)s) << 16;
    return c.f;
}

// BK=64 LDS layout (round-0-proven swizzle), double-buffered (64 KB).
//  1KB slab = 8 rows x 128B; logical chunk c of row r -> phys chunk c^(r&7).
//  Staging lane ln -> byte ln*16 fetches global chunk (ln&7)^(ln>>3) of row
//  ln>>3 (8 lanes = one full 128B row, coalesced).  Fragment (kk,quad,lm)
//  reads phys chunk (kk*4+quad)^(lm&7) (conflict-free).
//
// T1 XCD swizzle (CONFIRMED r14: FETCH 31.6->23.0 MB, MfmaUtil 25.7->28.0,
//  total 263.2 us best): remap fid -> w = (fid%8)*(NWG/8) + fid/8 (bijective,
//  NWG%8==0), role/o fastest inside w: each XCD owns a contiguous chunk whose
//  B working set fits its 4MB L2.  Pure relabeling -> bit-identical output.
//  This round: byte-identical confirmation run (r11/r13 protocol).

// ---------------------------------------------------------------------------
// Kernel 1 (merged): blocks 0..1023 = weights fp32->bf16 (+ ksum zero);
//                    blocks 1024..1279 = GroupNorm stats -> scale/shift.
__global__ __launch_bounds__(256) void pre_kernel(const float* __restrict__ x,
                                                  const float* __restrict__ gamma,
                                                  const float* __restrict__ beta,
                                                  const float* __restrict__ qw,
                                                  const float* __restrict__ pw,
                                                  unsigned short* __restrict__ qwb,
                                                  unsigned short* __restrict__ pwb,
                                                  float* __restrict__ ksum,
                                                  float* __restrict__ ss) {
    __shared__ float r1[256], r2[256];
    const int bid = blockIdx.x;
    const int t   = threadIdx.x;
    if (bid < 1024) {
        int i = (bid * 256 + t) * 4;
        if (i < O1 * CCH) {
            float4 v = *(const float4*)(qw + i);
            unsigned short o[4] = {f2bf(v.x), f2bf(v.y), f2bf(v.z), f2bf(v.w)};
            *(uint2*)(qwb + i) = *(uint2*)o;
        } else {
            int j = i - O1 * CCH;
            float4 v = *(const float4*)(pw + j);
            unsigned short o[4] = {f2bf(v.x), f2bf(v.y), f2bf(v.z), f2bf(v.w)};
            *(uint2*)(pwb + j) = *(uint2*)o;
        }
        if (bid == 0) {
            float4 z = {0.f, 0.f, 0.f, 0.f};
            #pragma unroll
            for (int l = 0; l < 4; ++l)
                *(float4*)(ksum + (l * 256 + t) * 4) = z;
        }
        return;
    }
    const int bg = bid - 1024;
    const float* base = x + (size_t)bg * (CPG * NSP);
    float s = 0.f, s2 = 0.f;
    #pragma unroll 4
    for (int i = 0; i < 64; ++i) {
        float4 v = *(const float4*)(base + (i * 256 + t) * 4);
        s  += v.x + v.y + v.z + v.w;
        s2 += v.x * v.x + v.y * v.y + v.z * v.z + v.w * v.w;
    }
    r1[t] = s; r2[t] = s2;
    __syncthreads();
    for (int off = 128; off > 0; off >>= 1) {
        if (t < off) { r1[t] += r1[t + off]; r2[t] += r2[t + off]; }
        __syncthreads();
    }
    if (t < CPG) {
        const float inv = 1.f / 65536.f;
        float mean = r1[0] * inv;
        float var  = r2[0] * inv - mean * mean;
        float rstd = rsqrtf(var + 1e-5f);
        int b = bg / NGROUPS, g = bg % NGROUPS;
        int c = g * CPG + t;
        float sc = gamma[c] * rstd;
        float sh = beta[c] - mean * sc;
        ss[(b * CCH + c) * 2]     = sc;
        ss[(b * CCH + c) * 2 + 1] = sh;
    }
}

// ---------------------------------------------------------------------------
// Kernel 2: xnT[b][n][c] bf16 = GroupNorm(x)[b][c][n] transposed.
__global__ __launch_bounds__(256) void xnT_kernel(const float* __restrict__ x,
                                                  const float* __restrict__ ss,
                                                  unsigned short* __restrict__ xnT) {
    const int n0 = blockIdx.x * 64, c0 = blockIdx.y * 64, b = blockIdx.z;
    const int t = threadIdx.x;
    __shared__ float tile[64][65];
    const float* xb  = x + ((size_t)b * CCH + c0) * NSP + n0;
    const float* ssb = ss + b * CCH * 2;

    const int lr = t / 16, lc = (t % 16) * 4;
    #pragma unroll
    for (int j = 0; j < 4; ++j) {
        int cr = j * 16 + lr;
        float4 v = *(const float4*)(xb + (size_t)cr * NSP + lc);
        float sc = ssb[(c0 + cr) * 2], sh = ssb[(c0 + cr) * 2 + 1];
        tile[cr][lc + 0] = v.x * sc + sh;
        tile[cr][lc + 1] = v.y * sc + sh;
        tile[cr][lc + 2] = v.z * sc + sh;
        tile[cr][lc + 3] = v.w * sc + sh;
    }
    __syncthreads();
    #pragma unroll
    for (int j = 0; j < 2; ++j) {
        int wd = j * 256 + t;
        int n  = wd >> 3;
        int cb = (wd & 7) * 8;
        ushort8 o;
        #pragma unroll
        for (int i = 0; i < 8; ++i) o[i] = f2bf(tile[cb + i][n]);
        *(ushort8*)(xnT + ((size_t)b * NSP + n0 + n) * CCH + c0 + cb) = o;
    }
}

// ---------------------------------------------------------------------------
// Kernel 3 (MERGED LAUNCH, BK=64 dbuf, XCD-swizzled): role yb < 8 -> k/v GEMM
// for head yb + in-block kv outer product; yb >= 8 -> q GEMM for o-tile
// (yb-8)*128.  Grid (32,12,8); work id remapped so each XCD owns 4 n-chunks
// x 12 roles (B-tile L2 reuse).  256 threads, 64 KB LDS.
__global__ __launch_bounds__(256) void gemm_qkv(const unsigned short* __restrict__ A,
                                                const unsigned short* __restrict__ Bt,
                                                const float* __restrict__ bias,
                                                unsigned short* __restrict__ qT,
                                                float* __restrict__ ksum,
                                                float* __restrict__ kvp) {
    // T1: dispatch id (x-fastest) -> XCD-chunked work id; 384 % 8 == 0.
    const int fid = blockIdx.y * 32 + blockIdx.x;       // 0..383
    const int w   = (fid & 7) * 48 + (fid >> 3);        // bijective remap
    const int yb  = w % 12;                             // role slice
    const int xb  = w / 12;                             // n-chunk

    const int n0 = xb * 128;
    const int b  = blockIdx.z;
    const int t  = threadIdx.x;
    const int wv = t >> 6, ln = t & 63;
    const int quad = ln >> 4, lm = ln & 15;
    const int wo = (wv >> 1) * 64, wn = (wv & 1) * 64;

    // buf0: A sh[0..8192), B sh[8192..16384); buf1: A sh[16384..24576), B ...
    __shared__ __align__(16) unsigned short sh[32768];

    float4v acc[4][4];
    #pragma unroll
    for (int i = 0; i < 4; ++i)
        #pragma unroll
        for (int j = 0; j < 4; ++j) acc[i][j] = {0.f, 0.f, 0.f, 0.f};

    const unsigned short* bBase = Bt + ((size_t)b * NSP + n0) * CCH;
    const int srow8 = ln >> 3;                          // row within slab
    const int scs   = ((ln & 7) ^ srow8) * 8;           // staging inv swizzle
    const int lmp   = lm & 7;                           // fragment row parity

    if (yb < 8) {
        // ================= k/v path =================
        const int h = yb;
        const unsigned short* aK = A + (size_t)(512 + h * 64) * CCH;
        const unsigned short* aV = A + (size_t)(1024 + h * 64) * CCH;

        // prologue: stage step 0 into buf0
        #pragma unroll
        for (int i = 0; i < 4; ++i) {
            int slab = wv + i * 4;                      // 0..15; <8 = k, >=8 = v
            const unsigned short* ab = (slab < 8)
                ? aK + (size_t)(slab * 8 + srow8) * CCH
                : aV + (size_t)((slab - 8) * 8 + srow8) * CCH;
            GLOAD_LDS16(ab + scs, sh + slab * 512);
            GLOAD_LDS16(bBase + (size_t)(slab * 8 + srow8) * CCH + scs,
                        sh + 8192 + slab * 512);
        }
        __syncthreads();

        int cur = 0;
        for (int step = 0; step < 8; ++step) {
            if (step < 7) {                             // prefetch next step
                const int nb = (cur ^ 1) * 16384;
                const int k1 = (step + 1) * 64;
                #pragma unroll
                for (int i = 0; i < 4; ++i) {
                    int slab = wv + i * 4;
                    const unsigned short* ab = (slab < 8)
                        ? aK + (size_t)(slab * 8 + srow8) * CCH
                        : aV + (size_t)((slab - 8) * 8 + srow8) * CCH;
                    GLOAD_LDS16(ab + k1 + scs, sh + nb + slab * 512);
                    GLOAD_LDS16(bBase + (size_t)(slab * 8 + srow8) * CCH + k1 + scs,
                                sh + nb + 8192 + slab * 512);
                }
            }
            const unsigned short* Ab = sh + cur * 16384;
            const unsigned short* Bb = Ab + 8192;
            #pragma unroll
            for (int kk = 0; kk < 2; ++kk) {
                const int sc8 = ((kk * 4 + quad) ^ lmp) * 8;
                short8 fw[4], fx[4];
                #pragma unroll
                for (int i = 0; i < 4; ++i)
                    fw[i] = *(const short8*)(Ab + (wo + i * 16 + lm) * 64 + sc8);
                #pragma unroll
                for (int j = 0; j < 4; ++j)
                    fx[j] = *(const short8*)(Bb + (wn + j * 16 + lm) * 64 + sc8);
                #pragma unroll
                for (int i = 0; i < 4; ++i)
                    #pragma unroll
                    for (int j = 0; j < 4; ++j)
                        acc[i][j] = __builtin_amdgcn_mfma_f32_16x16x32_bf16(
                            fx[j], fw[i], acc[i][j], 0, 0, 0);
            }
            if (step < 7) __syncthreads();
            cur ^= 1;
        }

        // ---- epilogue 1: bias + phi(k), write bf16 tile [c][n] to LDS ----
        __syncthreads();
        const bool isk = (wv < 2);
        const float* bptr = bias + (isk ? 512 : 1024) + h * 64;
        float ksp[4] = {0.f, 0.f, 0.f, 0.f};
        #pragma unroll
        for (int i = 0; i < 4; ++i) {
            float bs = bptr[i * 16 + lm];
            int row = wo + i * 16 + lm;
            #pragma unroll
            for (int j = 0; j < 4; ++j) {
                int n = wn + j * 16 + quad * 4;
                ushort4v pk;
                #pragma unroll
                for (int r = 0; r < 4; ++r) {
                    float v = acc[i][j][r] + bs;
                    if (isk) { v = phi_act(v); ksp[i] += v; }
                    pk[r] = f2bf(v);
                }
                int idx = row * 128 + ((((n >> 3) ^ (row & 15)) << 3) | (n & 7));
                *(ushort4v*)(sh + idx) = pk;
            }
        }
        if (isk) {
            #pragma unroll
            for (int i = 0; i < 4; ++i) {
                float s = ksp[i];
                s += __shfl_xor(s, 16);
                s += __shfl_xor(s, 32);
                if (quad == 0)
                    atomicAdd(ksum + b * CCH + h * 64 + i * 16 + lm, s);
            }
        }
        __syncthreads();

        // ---- epilogue 2: kv partial over 128 n, stored [d][e] ----
        const int wd = (wv >> 1) * 32, we = (wv & 1) * 32;
        float4v acc2[2][2];
        #pragma unroll
        for (int i = 0; i < 2; ++i)
            #pragma unroll
            for (int j = 0; j < 2; ++j) acc2[i][j] = {0.f, 0.f, 0.f, 0.f};

        #pragma unroll
        for (int ks = 0; ks < 4; ++ks) {
            short8 ka[2], vbf[2];
            #pragma unroll
            for (int i2 = 0; i2 < 2; ++i2) {
                int row = wd + i2 * 16 + lm;
                ka[i2] = *(const short8*)(sh + row * 128 +
                                          (((ks * 4 + quad) ^ (row & 15)) << 3));
            }
            #pragma unroll
            for (int j2 = 0; j2 < 2; ++j2) {
                int row = 64 + we + j2 * 16 + lm;
                vbf[j2] = *(const short8*)(sh + row * 128 +
                                           (((ks * 4 + quad) ^ (row & 15)) << 3));
            }
            #pragma unroll
            for (int i2 = 0; i2 < 2; ++i2)
                #pragma unroll
                for (int j2 = 0; j2 < 2; ++j2)
                    acc2[i2][j2] = __builtin_amdgcn_mfma_f32_16x16x32_bf16(
                        vbf[j2], ka[i2], acc2[i2][j2], 0, 0, 0);
        }

        const int chunk = xb;
        const int bh = b * 8 + h;
        #pragma unroll
        for (int i2 = 0; i2 < 2; ++i2)
            #pragma unroll
            for (int j2 = 0; j2 < 2; ++j2) {
                int d = wd + i2 * 16 + lm;
                int e = we + j2 * 16 + quad * 4;
                float4 r = {acc2[i2][j2][0], acc2[i2][j2][1],
                            acc2[i2][j2][2], acc2[i2][j2][3]};
                *(float4*)(kvp + ((size_t)(chunk * 64 + bh) * 64 + d) * 64 + e) = r;
            }
    } else {
        // ================= q path =================
        const int o0 = (yb - 8) * 128;
        const unsigned short* aBase = A + (size_t)o0 * CCH;

        #pragma unroll
        for (int i = 0; i < 4; ++i) {
            int slab = wv + i * 4;
            GLOAD_LDS16(aBase + (size_t)(slab * 8 + srow8) * CCH + scs,
                        sh + slab * 512);
            GLOAD_LDS16(bBase + (size_t)(slab * 8 + srow8) * CCH + scs,
                        sh + 8192 + slab * 512);
        }
        __syncthreads();

        int cur = 0;
        for (int step = 0; step < 8; ++step) {
            if (step < 7) {
                const int nb = (cur ^ 1) * 16384;
                const int k1 = (step + 1) * 64;
                #pragma unroll
                for (int i = 0; i < 4; ++i) {
                    int slab = wv + i * 4;
                    GLOAD_LDS16(aBase + (size_t)(slab * 8 + srow8) * CCH + k1 + scs,
                                sh + nb + slab * 512);
                    GLOAD_LDS16(bBase + (size_t)(slab * 8 + srow8) * CCH + k1 + scs,
                                sh + nb + 8192 + slab * 512);
                }
            }
            const unsigned short* Ab = sh + cur * 16384;
            const unsigned short* Bb = Ab + 8192;
            #pragma unroll
            for (int kk = 0; kk < 2; ++kk) {
                const int sc8 = ((kk * 4 + quad) ^ lmp) * 8;
                short8 fw[4], fx[4];
                #pragma unroll
                for (int i = 0; i < 4; ++i)
                    fw[i] = *(const short8*)(Ab + (wo + i * 16 + lm) * 64 + sc8);
                #pragma unroll
                for (int j = 0; j < 4; ++j)
                    fx[j] = *(const short8*)(Bb + (wn + j * 16 + lm) * 64 + sc8);
                #pragma unroll
                for (int i = 0; i < 4; ++i)
                    #pragma unroll
                    for (int j = 0; j < 4; ++j)
                        acc[i][j] = __builtin_amdgcn_mfma_f32_16x16x32_bf16(
                            fw[i], fx[j], acc[i][j], 0, 0, 0);
            }
            if (step < 7) __syncthreads();
            cur ^= 1;
        }

        // rows=o (quad*4+r), cols=n (lm). phi, store 4 consecutive o.
        #pragma unroll
        for (int i = 0; i < 4; ++i) {
            int ob = o0 + wo + i * 16 + quad * 4;
            float4 b4 = *(const float4*)(bias + ob);
            float bs[4] = {b4.x, b4.y, b4.z, b4.w};
            #pragma unroll
            for (int j = 0; j < 4; ++j) {
                int n = n0 + wn + j * 16 + lm;
                ushort4v pk;
                #pragma unroll
                for (int r = 0; r < 4; ++r)
                    pk[r] = f2bf(phi_act(acc[i][j][r] + bs[r]));
                *(ushort4v*)(qT + ((size_t)b * NSP + n) * CCH + ob) = pk;
            }
        }
    }
}

// ---------------------------------------------------------------------------
// Kernel 4: kv-reduce + fold into proj weights.  grid = 128 (bh 64 x o-half 2):
//   phase A: per bh, sum 32 kvp partials -> bf16 LDS tile (duplicated by the
//            2 o-half blocks; kvp is L2/L3-hot) -- same sum order as before.
//   phase B: M_b[o][h*64+d] = sum_e kv[d][e]*W[o][h*64+e] for 256 o.
__global__ __launch_bounds__(256) void post_kernel(const float* __restrict__ kvp,
                                                   const unsigned short* __restrict__ pwb,
                                                   unsigned short* __restrict__ Mw) {
    const int t = threadIdx.x;
    __shared__ __align__(16) unsigned short kvs[64 * 64];

    const int bh = blockIdx.x >> 1;
    const int half = blockIdx.x & 1;
    const int b = bh >> 3, h = bh & 7;
    const int wv = t >> 6, ln = t & 63;
    const int quad = ln >> 4, lm = ln & 15;

    // ---- phase A: reduce 32 chunk partials, stage bf16 swizzled ----
    {
        const int d = t >> 2, e0 = (t & 3) * 16;
        float4 s0 = {0.f, 0.f, 0.f, 0.f}, s1 = s0, s2 = s0, s3 = s0;
        for (int p = 0; p < 32; ++p) {
            const float* src = kvp + ((size_t)(p * 64 + bh) * 64 + d) * 64 + e0;
            float4 v0 = *(const float4*)(src);
            float4 v1 = *(const float4*)(src + 4);
            float4 v2 = *(const float4*)(src + 8);
            float4 v3 = *(const float4*)(src + 12);
            s0.x += v0.x; s0.y += v0.y; s0.z += v0.z; s0.w += v0.w;
            s1.x += v1.x; s1.y += v1.y; s1.z += v1.z; s1.w += v1.w;
            s2.x += v2.x; s2.y += v2.y; s2.z += v2.z; s2.w += v2.w;
            s3.x += v3.x; s3.y += v3.y; s3.z += v3.z; s3.w += v3.w;
        }
        ushort8 o0 = {f2bf(s0.x), f2bf(s0.y), f2bf(s0.z), f2bf(s0.w),
                      f2bf(s1.x), f2bf(s1.y), f2bf(s1.z), f2bf(s1.w)};
        ushort8 o1 = {f2bf(s2.x), f2bf(s2.y), f2bf(s2.z), f2bf(s2.w),
                      f2bf(s3.x), f2bf(s3.y), f2bf(s3.z), f2bf(s3.w)};
        int c0 = e0 >> 3;   // chunk swizzle: phys chunk = c ^ (d&7)
        *(ushort8*)(kvs + d * 64 + ((c0 ^ (d & 7)) << 3))       = o0;
        *(ushort8*)(kvs + d * 64 + (((c0 + 1) ^ (d & 7)) << 3)) = o1;
    }
    __syncthreads();

    // ---- phase B: fold into proj weights, this block's 256 o ----
    short8 ka[4][2];
    #pragma unroll
    for (int i = 0; i < 4; ++i)
        #pragma unroll
        for (int kk = 0; kk < 2; ++kk) {
            int d = i * 16 + lm;
            ka[i][kk] = *(const short8*)(kvs + d * 64 +
                        (((kk * 4 + quad) ^ (lm & 7)) << 3));
        }
    const int ob = half * 256 + wv * 64;
    short8 fw[4][2];
    #pragma unroll
    for (int j = 0; j < 4; ++j)
        #pragma unroll
        for (int kk = 0; kk < 2; ++kk) {
            int o = ob + j * 16 + lm;
            fw[j][kk] = *(const short8*)(pwb + (size_t)o * CCH + h * 64 +
                                         kk * 32 + quad * 8);
        }
    float4v acc[4][4];
    #pragma unroll
    for (int i = 0; i < 4; ++i)
        #pragma unroll
        for (int j = 0; j < 4; ++j) acc[i][j] = {0.f, 0.f, 0.f, 0.f};
    #pragma unroll
    for (int kk = 0; kk < 2; ++kk)
        #pragma unroll
        for (int i = 0; i < 4; ++i)
            #pragma unroll
            for (int j = 0; j < 4; ++j)
                acc[i][j] = __builtin_amdgcn_mfma_f32_16x16x32_bf16(
                    ka[i][kk], fw[j][kk], acc[i][j], 0, 0, 0);
    // rows=d (quad*4+r), cols=o (lm): store 4 consecutive c at row o.
    #pragma unroll
    for (int i = 0; i < 4; ++i)
        #pragma unroll
        for (int j = 0; j < 4; ++j) {
            int o = ob + j * 16 + lm;
            int c = h * 64 + i * 16 + quad * 4;
            ushort4v pk;
            #pragma unroll
            for (int r = 0; r < 4; ++r) pk[r] = f2bf(acc[i][j][r]);
            *(ushort4v*)(Mw + ((size_t)b * CCH + o) * CCH + c) = pk;
        }
}

// ---------------------------------------------------------------------------
// Kernel 5: proj GEMM on qT with per-batch folded weights M_b (BK=64 dbuf,
// XCD-swizzled).  out[n][o] = (sum_c q[n][c] M_b[o][c]) / den[n] + bias + resid
// den[n] computed in the K-loop from staged B fragments (shfl_xor reduce).
__global__ __launch_bounds__(256) void gemm_proj(const unsigned short* __restrict__ Mw,
                                                 const unsigned short* __restrict__ Bt,
                                                 const float* __restrict__ bias,
                                                 const float* __restrict__ ksum,
                                                 const float* __restrict__ resid,
                                                 float* __restrict__ outF) {
    // T1: dispatch id -> XCD-chunked work id; 128 % 8 == 0; o fastest.
    const int fid = blockIdx.y * 32 + blockIdx.x;       // 0..127
    const int w   = (fid & 7) * 16 + (fid >> 3);        // bijective remap
    const int o0  = (w & 3) * 128;
    const int n0  = (w >> 2) * 128;

    const int b  = blockIdx.z;
    const int t  = threadIdx.x;
    const int wv = t >> 6, ln = t & 63;
    const int quad = ln >> 4, lm = ln & 15;
    const int wo = (wv >> 1) * 64, wn = (wv & 1) * 64;

    __shared__ __align__(16) unsigned short sh[32768];

    float4v acc[4][4];
    #pragma unroll
    for (int i = 0; i < 4; ++i)
        #pragma unroll
        for (int j = 0; j < 4; ++j) acc[i][j] = {0.f, 0.f, 0.f, 0.f};
    float den4[4] = {0.f, 0.f, 0.f, 0.f};

    const unsigned short* aBase = Mw + ((size_t)b * CCH + o0) * CCH;
    const unsigned short* bBase = Bt + ((size_t)b * NSP + n0) * CCH;
    const float* kssB = ksum + b * CCH + quad * 8;

    const int srow8 = ln >> 3;
    const int scs   = ((ln & 7) ^ srow8) * 8;
    const int lmp   = lm & 7;

    #pragma unroll
    for (int i = 0; i < 4; ++i) {
        int slab = wv + i * 4;
        GLOAD_LDS16(aBase + (size_t)(slab * 8 + srow8) * CCH + scs,
                    sh + slab * 512);
        GLOAD_LDS16(bBase + (size_t)(slab * 8 + srow8) * CCH + scs,
                    sh + 8192 + slab * 512);
    }
    __syncthreads();

    int cur = 0;
    for (int step = 0; step < 8; ++step) {
        if (step < 7) {
            const int nb = (cur ^ 1) * 16384;
            const int k1 = (step + 1) * 64;
            #pragma unroll
            for (int i = 0; i < 4; ++i) {
                int slab = wv + i * 4;
                GLOAD_LDS16(aBase + (size_t)(slab * 8 + srow8) * CCH + k1 + scs,
                            sh + nb + slab * 512);
                GLOAD_LDS16(bBase + (size_t)(slab * 8 + srow8) * CCH + k1 + scs,
                            sh + nb + 8192 + slab * 512);
            }
        }
        const unsigned short* Ab = sh + cur * 16384;
        const unsigned short* Bb = Ab + 8192;
        #pragma unroll
        for (int kk = 0; kk < 2; ++kk) {
            const int sc8 = ((kk * 4 + quad) ^ lmp) * 8;
            short8 fw[4], fx[4];
            #pragma unroll
            for (int i = 0; i < 4; ++i)
                fw[i] = *(const short8*)(Ab + (wo + i * 16 + lm) * 64 + sc8);
            #pragma unroll
            for (int j = 0; j < 4; ++j)
                fx[j] = *(const short8*)(Bb + (wn + j * 16 + lm) * 64 + sc8);
            // den partials (logical k = step*64 + kk*32 + quad*8 + l)
            {
                float4 ka4 = *(const float4*)(kssB + step * 64 + kk * 32);
                float4 kb4 = *(const float4*)(kssB + step * 64 + kk * 32 + 4);
                float kf[8] = {ka4.x, ka4.y, ka4.z, ka4.w,
                               kb4.x, kb4.y, kb4.z, kb4.w};
                #pragma unroll
                for (int j = 0; j < 4; ++j)
                    #pragma unroll
                    for (int l = 0; l < 8; ++l)
                        den4[j] += bf2f((unsigned short)fx[j][l]) * kf[l];
            }
            #pragma unroll
            for (int i = 0; i < 4; ++i)
                #pragma unroll
                for (int j = 0; j < 4; ++j)
                    acc[i][j] = __builtin_amdgcn_mfma_f32_16x16x32_bf16(
                        fx[j], fw[i], acc[i][j], 0, 0, 0);
        }
        if (step < 7) __syncthreads();
        cur ^= 1;
    }

    // complete den: sum the 4 quad partials; every lane then holds den for
    // its lm row; epilogue rows n = wn+j*16+quad*4+r fetch lane quad*4+r.
    #pragma unroll
    for (int j = 0; j < 4; ++j) {
        den4[j] += __shfl_xor(den4[j], 16);
        den4[j] += __shfl_xor(den4[j], 32);
    }
    float4v rden[4];
    #pragma unroll
    for (int j = 0; j < 4; ++j)
        #pragma unroll
        for (int r = 0; r < 4; ++r)
            rden[j][r] = 1.f / (__shfl(den4[j], quad * 4 + r) + 1e-6f);

    // rows=n (quad*4+r), cols=o (lm). den-divide + bias + resid epilogue.
    #pragma unroll
    for (int i = 0; i < 4; ++i) {
        int o = o0 + wo + i * 16 + lm;
        float bs = bias[o];
        #pragma unroll
        for (int j = 0; j < 4; ++j) {
            int n = n0 + wn + j * 16 + quad * 4;
            size_t off = ((size_t)b * CCH + o) * NSP + n;
            float4 rv = *(const float4*)(resid + off);
            float4 w2 = {acc[i][j][0] * rden[j][0] + bs + rv.x,
                         acc[i][j][1] * rden[j][1] + bs + rv.y,
                         acc[i][j][2] * rden[j][2] + bs + rv.z,
                         acc[i][j][3] * rden[j][3] + bs + rv.w};
            *(float4*)(outF + off) = w2;
        }
    }
}

// ---------------------------------------------------------------------------
extern "C" void kernel_launch(void* const* d_in, const int* in_sizes, int n_in,
                              void* d_out, int out_size, void* d_ws, size_t ws_size,
                              hipStream_t stream) {
    const float* x      = (const float*)d_in[0];
    const float* gamma  = (const float*)d_in[1];
    const float* beta   = (const float*)d_in[2];
    const float* qkv_w  = (const float*)d_in[3];
    const float* qkv_b  = (const float*)d_in[4];
    const float* proj_w = (const float*)d_in[5];
    const float* proj_b = (const float*)d_in[6];
    float* out = (float*)d_out;

    // workspace layout (float units)
    float* ws   = (float*)d_ws;
    float* ss   = ws;                                   //    8192
    float* ksum = ss + 8192;                            //    4096
    float* kvp  = ksum + 4096;                          // 32*64*64*64
    unsigned short* xnT  = (unsigned short*)(kvp + (size_t)32 * 64 * 64 * 64);
    unsigned short* qT   = xnT + (size_t)BATCH * NSP * CCH;
    unsigned short* Mw   = qT  + (size_t)BATCH * NSP * CCH;
    unsigned short* wqb  = Mw + (size_t)BATCH * CCH * CCH;
    unsigned short* wpb  = wqb + (size_t)O1 * CCH;

    pre_kernel<<<1280, 256, 0, stream>>>(x, gamma, beta, qkv_w, proj_w,
                                         wqb, wpb, ksum, ss);
    xnT_kernel<<<dim3(NSP / 64, CCH / 64, BATCH), 256, 0, stream>>>(x, ss, xnT);

    gemm_qkv<<<dim3(NSP / 128, 12, BATCH), 256, 0, stream>>>(
        wqb, xnT, qkv_b, qT, ksum, kvp);

    post_kernel<<<128, 256, 0, stream>>>(kvp, wpb, Mw);

    gemm_proj<<<dim3(NSP / 128, CCH / 128, BATCH), 256, 0, stream>>>(
        Mw, qT, proj_b, ksum, x, out);
}

// Round 16
// 262.704 us; speedup vs baseline: 1.0021x; 1.0021x over previous
//
#include <hip/hip_runtime.h>
#include <math.h>

#define BATCH   8
#define CCH     512
#define NHEADS  8
#define HD      64
#define NGROUPS 32
#define CPG     16
#define NSP     4096      // H*W
#define O1      1536      // 3*C

typedef __attribute__((ext_vector_type(8))) short          short8;
typedef __attribute__((ext_vector_type(8))) unsigned short ushort8;
typedef __attribute__((ext_vector_type(4))) unsigned short ushort4v;
typedef __attribute__((ext_vector_type(4))) float          float4v;

#define GLOAD_LDS16(g, s) __builtin_amdgcn_global_load_lds(                   \
    (const __attribute__((address_space(1))) void*)(g),                       \
    (__attribute__((address_space(3))) void*)(s), 16, 0, 0)

// ---------------------------------------------------------------------------
__device__ __forceinline__ float phi_act(float v) {   // elu(x)+1
    return v > 0.f ? v + 1.f : __expf(v);
}
__device__ __forceinline__ unsigned short f2bf(float f) {  // RNE fp32->bf16
    union { float f; unsigned int u; } c; c.f = f;
    unsigned int u = c.u;
    u += 0x7fffu + ((u >> 16) & 1u);
    return (unsigned short)(u >> 16);
}
__device__ __forceinline__ float bf2f(unsigned short s) {
    union { unsigned int u; float f; } c; c.u = ((unsigned int)s) << 16;
    return c.f;
}

// BK=64 LDS layout (round-0-proven swizzle), double-buffered (64 KB).
//  1KB slab = 8 rows x 128B; logical chunk c of row r -> phys chunk c^(r&7).
//  Staging lane ln -> byte ln*16 fetches global chunk (ln&7)^(ln>>3) of row
//  ln>>3 (8 lanes = one full 128B row, coalesced).  Fragment (kk,quad,lm)
//  reads phys chunk (kk*4+quad)^(lm&7) (conflict-free).
//
// T1 XCD swizzle (CONFIRMED r14+r15: FETCH 31.6->23.0 MB, MfmaUtil 25.7->28.5,
//  total 263.2 us reproduced to 0.01%): remap fid -> w = (fid%8)*(NWG/8)+fid/8
//  (bijective, NWG%8==0), role/o fastest inside w: each XCD owns a contiguous
//  chunk whose B working set fits its 4MB L2.  Bit-identical output.
//  This round adds the same remap to post_kernel (bh-pair -> same XCD so the
//  second o-half's 512KB kvp re-read is an L2 hit; 8 bh x 512KB = 4MB = L2).

// ---------------------------------------------------------------------------
// Kernel 1 (merged): blocks 0..1023 = weights fp32->bf16 (+ ksum zero);
//                    blocks 1024..1279 = GroupNorm stats -> scale/shift.
__global__ __launch_bounds__(256) void pre_kernel(const float* __restrict__ x,
                                                  const float* __restrict__ gamma,
                                                  const float* __restrict__ beta,
                                                  const float* __restrict__ qw,
                                                  const float* __restrict__ pw,
                                                  unsigned short* __restrict__ qwb,
                                                  unsigned short* __restrict__ pwb,
                                                  float* __restrict__ ksum,
                                                  float* __restrict__ ss) {
    __shared__ float r1[256], r2[256];
    const int bid = blockIdx.x;
    const int t   = threadIdx.x;
    if (bid < 1024) {
        int i = (bid * 256 + t) * 4;
        if (i < O1 * CCH) {
            float4 v = *(const float4*)(qw + i);
            unsigned short o[4] = {f2bf(v.x), f2bf(v.y), f2bf(v.z), f2bf(v.w)};
            *(uint2*)(qwb + i) = *(uint2*)o;
        } else {
            int j = i - O1 * CCH;
            float4 v = *(const float4*)(pw + j);
            unsigned short o[4] = {f2bf(v.x), f2bf(v.y), f2bf(v.z), f2bf(v.w)};
            *(uint2*)(pwb + j) = *(uint2*)o;
        }
        if (bid == 0) {
            float4 z = {0.f, 0.f, 0.f, 0.f};
            #pragma unroll
            for (int l = 0; l < 4; ++l)
                *(float4*)(ksum + (l * 256 + t) * 4) = z;
        }
        return;
    }
    const int bg = bid - 1024;
    const float* base = x + (size_t)bg * (CPG * NSP);
    float s = 0.f, s2 = 0.f;
    #pragma unroll 4
    for (int i = 0; i < 64; ++i) {
        float4 v = *(const float4*)(base + (i * 256 + t) * 4);
        s  += v.x + v.y + v.z + v.w;
        s2 += v.x * v.x + v.y * v.y + v.z * v.z + v.w * v.w;
    }
    r1[t] = s; r2[t] = s2;
    __syncthreads();
    for (int off = 128; off > 0; off >>= 1) {
        if (t < off) { r1[t] += r1[t + off]; r2[t] += r2[t + off]; }
        __syncthreads();
    }
    if (t < CPG) {
        const float inv = 1.f / 65536.f;
        float mean = r1[0] * inv;
        float var  = r2[0] * inv - mean * mean;
        float rstd = rsqrtf(var + 1e-5f);
        int b = bg / NGROUPS, g = bg % NGROUPS;
        int c = g * CPG + t;
        float sc = gamma[c] * rstd;
        float sh = beta[c] - mean * sc;
        ss[(b * CCH + c) * 2]     = sc;
        ss[(b * CCH + c) * 2 + 1] = sh;
    }
}

// ---------------------------------------------------------------------------
// Kernel 2: xnT[b][n][c] bf16 = GroupNorm(x)[b][c][n] transposed.
__global__ __launch_bounds__(256) void xnT_kernel(const float* __restrict__ x,
                                                  const float* __restrict__ ss,
                                                  unsigned short* __restrict__ xnT) {
    const int n0 = blockIdx.x * 64, c0 = blockIdx.y * 64, b = blockIdx.z;
    const int t = threadIdx.x;
    __shared__ float tile[64][65];
    const float* xb  = x + ((size_t)b * CCH + c0) * NSP + n0;
    const float* ssb = ss + b * CCH * 2;

    const int lr = t / 16, lc = (t % 16) * 4;
    #pragma unroll
    for (int j = 0; j < 4; ++j) {
        int cr = j * 16 + lr;
        float4 v = *(const float4*)(xb + (size_t)cr * NSP + lc);
        float sc = ssb[(c0 + cr) * 2], sh = ssb[(c0 + cr) * 2 + 1];
        tile[cr][lc + 0] = v.x * sc + sh;
        tile[cr][lc + 1] = v.y * sc + sh;
        tile[cr][lc + 2] = v.z * sc + sh;
        tile[cr][lc + 3] = v.w * sc + sh;
    }
    __syncthreads();
    #pragma unroll
    for (int j = 0; j < 2; ++j) {
        int wd = j * 256 + t;
        int n  = wd >> 3;
        int cb = (wd & 7) * 8;
        ushort8 o;
        #pragma unroll
        for (int i = 0; i < 8; ++i) o[i] = f2bf(tile[cb + i][n]);
        *(ushort8*)(xnT + ((size_t)b * NSP + n0 + n) * CCH + c0 + cb) = o;
    }
}

// ---------------------------------------------------------------------------
// Kernel 3 (MERGED LAUNCH, BK=64 dbuf, XCD-swizzled): role yb < 8 -> k/v GEMM
// for head yb + in-block kv outer product; yb >= 8 -> q GEMM for o-tile
// (yb-8)*128.  Grid (32,12,8); work id remapped so each XCD owns 4 n-chunks
// x 12 roles (B-tile L2 reuse).  256 threads, 64 KB LDS.
__global__ __launch_bounds__(256) void gemm_qkv(const unsigned short* __restrict__ A,
                                                const unsigned short* __restrict__ Bt,
                                                const float* __restrict__ bias,
                                                unsigned short* __restrict__ qT,
                                                float* __restrict__ ksum,
                                                float* __restrict__ kvp) {
    // T1: dispatch id (x-fastest) -> XCD-chunked work id; 384 % 8 == 0.
    const int fid = blockIdx.y * 32 + blockIdx.x;       // 0..383
    const int w   = (fid & 7) * 48 + (fid >> 3);        // bijective remap
    const int yb  = w % 12;                             // role slice
    const int xb  = w / 12;                             // n-chunk

    const int n0 = xb * 128;
    const int b  = blockIdx.z;
    const int t  = threadIdx.x;
    const int wv = t >> 6, ln = t & 63;
    const int quad = ln >> 4, lm = ln & 15;
    const int wo = (wv >> 1) * 64, wn = (wv & 1) * 64;

    // buf0: A sh[0..8192), B sh[8192..16384); buf1: A sh[16384..24576), B ...
    __shared__ __align__(16) unsigned short sh[32768];

    float4v acc[4][4];
    #pragma unroll
    for (int i = 0; i < 4; ++i)
        #pragma unroll
        for (int j = 0; j < 4; ++j) acc[i][j] = {0.f, 0.f, 0.f, 0.f};

    const unsigned short* bBase = Bt + ((size_t)b * NSP + n0) * CCH;
    const int srow8 = ln >> 3;                          // row within slab
    const int scs   = ((ln & 7) ^ srow8) * 8;           // staging inv swizzle
    const int lmp   = lm & 7;                           // fragment row parity

    if (yb < 8) {
        // ================= k/v path =================
        const int h = yb;
        const unsigned short* aK = A + (size_t)(512 + h * 64) * CCH;
        const unsigned short* aV = A + (size_t)(1024 + h * 64) * CCH;

        // prologue: stage step 0 into buf0
        #pragma unroll
        for (int i = 0; i < 4; ++i) {
            int slab = wv + i * 4;                      // 0..15; <8 = k, >=8 = v
            const unsigned short* ab = (slab < 8)
                ? aK + (size_t)(slab * 8 + srow8) * CCH
                : aV + (size_t)((slab - 8) * 8 + srow8) * CCH;
            GLOAD_LDS16(ab + scs, sh + slab * 512);
            GLOAD_LDS16(bBase + (size_t)(slab * 8 + srow8) * CCH + scs,
                        sh + 8192 + slab * 512);
        }
        __syncthreads();

        int cur = 0;
        for (int step = 0; step < 8; ++step) {
            if (step < 7) {                             // prefetch next step
                const int nb = (cur ^ 1) * 16384;
                const int k1 = (step + 1) * 64;
                #pragma unroll
                for (int i = 0; i < 4; ++i) {
                    int slab = wv + i * 4;
                    const unsigned short* ab = (slab < 8)
                        ? aK + (size_t)(slab * 8 + srow8) * CCH
                        : aV + (size_t)((slab - 8) * 8 + srow8) * CCH;
                    GLOAD_LDS16(ab + k1 + scs, sh + nb + slab * 512);
                    GLOAD_LDS16(bBase + (size_t)(slab * 8 + srow8) * CCH + k1 + scs,
                                sh + nb + 8192 + slab * 512);
                }
            }
            const unsigned short* Ab = sh + cur * 16384;
            const unsigned short* Bb = Ab + 8192;
            #pragma unroll
            for (int kk = 0; kk < 2; ++kk) {
                const int sc8 = ((kk * 4 + quad) ^ lmp) * 8;
                short8 fw[4], fx[4];
                #pragma unroll
                for (int i = 0; i < 4; ++i)
                    fw[i] = *(const short8*)(Ab + (wo + i * 16 + lm) * 64 + sc8);
                #pragma unroll
                for (int j = 0; j < 4; ++j)
                    fx[j] = *(const short8*)(Bb + (wn + j * 16 + lm) * 64 + sc8);
                #pragma unroll
                for (int i = 0; i < 4; ++i)
                    #pragma unroll
                    for (int j = 0; j < 4; ++j)
                        acc[i][j] = __builtin_amdgcn_mfma_f32_16x16x32_bf16(
                            fx[j], fw[i], acc[i][j], 0, 0, 0);
            }
            if (step < 7) __syncthreads();
            cur ^= 1;
        }

        // ---- epilogue 1: bias + phi(k), write bf16 tile [c][n] to LDS ----
        __syncthreads();
        const bool isk = (wv < 2);
        const float* bptr = bias + (isk ? 512 : 1024) + h * 64;
        float ksp[4] = {0.f, 0.f, 0.f, 0.f};
        #pragma unroll
        for (int i = 0; i < 4; ++i) {
            float bs = bptr[i * 16 + lm];
            int row = wo + i * 16 + lm;
            #pragma unroll
            for (int j = 0; j < 4; ++j) {
                int n = wn + j * 16 + quad * 4;
                ushort4v pk;
                #pragma unroll
                for (int r = 0; r < 4; ++r) {
                    float v = acc[i][j][r] + bs;
                    if (isk) { v = phi_act(v); ksp[i] += v; }
                    pk[r] = f2bf(v);
                }
                int idx = row * 128 + ((((n >> 3) ^ (row & 15)) << 3) | (n & 7));
                *(ushort4v*)(sh + idx) = pk;
            }
        }
        if (isk) {
            #pragma unroll
            for (int i = 0; i < 4; ++i) {
                float s = ksp[i];
                s += __shfl_xor(s, 16);
                s += __shfl_xor(s, 32);
                if (quad == 0)
                    atomicAdd(ksum + b * CCH + h * 64 + i * 16 + lm, s);
            }
        }
        __syncthreads();

        // ---- epilogue 2: kv partial over 128 n, stored [d][e] ----
        const int wd = (wv >> 1) * 32, we = (wv & 1) * 32;
        float4v acc2[2][2];
        #pragma unroll
        for (int i = 0; i < 2; ++i)
            #pragma unroll
            for (int j = 0; j < 2; ++j) acc2[i][j] = {0.f, 0.f, 0.f, 0.f};

        #pragma unroll
        for (int ks = 0; ks < 4; ++ks) {
            short8 ka[2], vbf[2];
            #pragma unroll
            for (int i2 = 0; i2 < 2; ++i2) {
                int row = wd + i2 * 16 + lm;
                ka[i2] = *(const short8*)(sh + row * 128 +
                                          (((ks * 4 + quad) ^ (row & 15)) << 3));
            }
            #pragma unroll
            for (int j2 = 0; j2 < 2; ++j2) {
                int row = 64 + we + j2 * 16 + lm;
                vbf[j2] = *(const short8*)(sh + row * 128 +
                                           (((ks * 4 + quad) ^ (row & 15)) << 3));
            }
            #pragma unroll
            for (int i2 = 0; i2 < 2; ++i2)
                #pragma unroll
                for (int j2 = 0; j2 < 2; ++j2)
                    acc2[i2][j2] = __builtin_amdgcn_mfma_f32_16x16x32_bf16(
                        vbf[j2], ka[i2], acc2[i2][j2], 0, 0, 0);
        }

        const int chunk = xb;
        const int bh = b * 8 + h;
        #pragma unroll
        for (int i2 = 0; i2 < 2; ++i2)
            #pragma unroll
            for (int j2 = 0; j2 < 2; ++j2) {
                int d = wd + i2 * 16 + lm;
                int e = we + j2 * 16 + quad * 4;
                float4 r = {acc2[i2][j2][0], acc2[i2][j2][1],
                            acc2[i2][j2][2], acc2[i2][j2][3]};
                *(float4*)(kvp + ((size_t)(chunk * 64 + bh) * 64 + d) * 64 + e) = r;
            }
    } else {
        // ================= q path =================
        const int o0 = (yb - 8) * 128;
        const unsigned short* aBase = A + (size_t)o0 * CCH;

        #pragma unroll
        for (int i = 0; i < 4; ++i) {
            int slab = wv + i * 4;
            GLOAD_LDS16(aBase + (size_t)(slab * 8 + srow8) * CCH + scs,
                        sh + slab * 512);
            GLOAD_LDS16(bBase + (size_t)(slab * 8 + srow8) * CCH + scs,
                        sh + 8192 + slab * 512);
        }
        __syncthreads();

        int cur = 0;
        for (int step = 0; step < 8; ++step) {
            if (step < 7) {
                const int nb = (cur ^ 1) * 16384;
                const int k1 = (step + 1) * 64;
                #pragma unroll
                for (int i = 0; i < 4; ++i) {
                    int slab = wv + i * 4;
                    GLOAD_LDS16(aBase + (size_t)(slab * 8 + srow8) * CCH + k1 + scs,
                                sh + nb + slab * 512);
                    GLOAD_LDS16(bBase + (size_t)(slab * 8 + srow8) * CCH + k1 + scs,
                                sh + nb + 8192 + slab * 512);
                }
            }
            const unsigned short* Ab = sh + cur * 16384;
            const unsigned short* Bb = Ab + 8192;
            #pragma unroll
            for (int kk = 0; kk < 2; ++kk) {
                const int sc8 = ((kk * 4 + quad) ^ lmp) * 8;
                short8 fw[4], fx[4];
                #pragma unroll
                for (int i = 0; i < 4; ++i)
                    fw[i] = *(const short8*)(Ab + (wo + i * 16 + lm) * 64 + sc8);
                #pragma unroll
                for (int j = 0; j < 4; ++j)
                    fx[j] = *(const short8*)(Bb + (wn + j * 16 + lm) * 64 + sc8);
                #pragma unroll
                for (int i = 0; i < 4; ++i)
                    #pragma unroll
                    for (int j = 0; j < 4; ++j)
                        acc[i][j] = __builtin_amdgcn_mfma_f32_16x16x32_bf16(
                            fw[i], fx[j], acc[i][j], 0, 0, 0);
            }
            if (step < 7) __syncthreads();
            cur ^= 1;
        }

        // rows=o (quad*4+r), cols=n (lm). phi, store 4 consecutive o.
        #pragma unroll
        for (int i = 0; i < 4; ++i) {
            int ob = o0 + wo + i * 16 + quad * 4;
            float4 b4 = *(const float4*)(bias + ob);
            float bs[4] = {b4.x, b4.y, b4.z, b4.w};
            #pragma unroll
            for (int j = 0; j < 4; ++j) {
                int n = n0 + wn + j * 16 + lm;
                ushort4v pk;
                #pragma unroll
                for (int r = 0; r < 4; ++r)
                    pk[r] = f2bf(phi_act(acc[i][j][r] + bs[r]));
                *(ushort4v*)(qT + ((size_t)b * NSP + n) * CCH + ob) = pk;
            }
        }
    }
}

// ---------------------------------------------------------------------------
// Kernel 4: kv-reduce + fold into proj weights.  grid = 128 (bh 64 x o-half 2),
// XCD-paired: remap so both o-half blocks of a bh land on the SAME XCD (the
// second half's 512KB kvp re-read becomes an L2 hit; 8 bh/XCD x 512KB = 4MB).
//   phase A: per bh, sum 32 kvp partials -> bf16 LDS tile (same sum order).
//   phase B: M_b[o][h*64+d] = sum_e kv[d][e]*W[o][h*64+e] for 256 o.
__global__ __launch_bounds__(256) void post_kernel(const float* __restrict__ kvp,
                                                   const unsigned short* __restrict__ pwb,
                                                   unsigned short* __restrict__ Mw) {
    const int t = threadIdx.x;
    __shared__ __align__(16) unsigned short kvs[64 * 64];

    // T1 pairing: fid -> w chunked by XCD; bh-pairs (w=2m,2m+1) stay in-chunk.
    const int fid = blockIdx.x;                          // 0..127
    const int w   = (fid & 7) * 16 + (fid >> 3);         // bijective remap
    const int bh  = w >> 1;
    const int half = w & 1;
    const int b = bh >> 3, h = bh & 7;
    const int wv = t >> 6, ln = t & 63;
    const int quad = ln >> 4, lm = ln & 15;

    // ---- phase A: reduce 32 chunk partials, stage bf16 swizzled ----
    {
        const int d = t >> 2, e0 = (t & 3) * 16;
        float4 s0 = {0.f, 0.f, 0.f, 0.f}, s1 = s0, s2 = s0, s3 = s0;
        for (int p = 0; p < 32; ++p) {
            const float* src = kvp + ((size_t)(p * 64 + bh) * 64 + d) * 64 + e0;
            float4 v0 = *(const float4*)(src);
            float4 v1 = *(const float4*)(src + 4);
            float4 v2 = *(const float4*)(src + 8);
            float4 v3 = *(const float4*)(src + 12);
            s0.x += v0.x; s0.y += v0.y; s0.z += v0.z; s0.w += v0.w;
            s1.x += v1.x; s1.y += v1.y; s1.z += v1.z; s1.w += v1.w;
            s2.x += v2.x; s2.y += v2.y; s2.z += v2.z; s2.w += v2.w;
            s3.x += v3.x; s3.y += v3.y; s3.z += v3.z; s3.w += v3.w;
        }
        ushort8 o0 = {f2bf(s0.x), f2bf(s0.y), f2bf(s0.z), f2bf(s0.w),
                      f2bf(s1.x), f2bf(s1.y), f2bf(s1.z), f2bf(s1.w)};
        ushort8 o1 = {f2bf(s2.x), f2bf(s2.y), f2bf(s2.z), f2bf(s2.w),
                      f2bf(s3.x), f2bf(s3.y), f2bf(s3.z), f2bf(s3.w)};
        int c0 = e0 >> 3;   // chunk swizzle: phys chunk = c ^ (d&7)
        *(ushort8*)(kvs + d * 64 + ((c0 ^ (d & 7)) << 3))       = o0;
        *(ushort8*)(kvs + d * 64 + (((c0 + 1) ^ (d & 7)) << 3)) = o1;
    }
    __syncthreads();

    // ---- phase B: fold into proj weights, this block's 256 o ----
    short8 ka[4][2];
    #pragma unroll
    for (int i = 0; i < 4; ++i)
        #pragma unroll
        for (int kk = 0; kk < 2; ++kk) {
            int d = i * 16 + lm;
            ka[i][kk] = *(const short8*)(kvs + d * 64 +
                        (((kk * 4 + quad) ^ (lm & 7)) << 3));
        }
    const int ob = half * 256 + wv * 64;
    short8 fw[4][2];
    #pragma unroll
    for (int j = 0; j < 4; ++j)
        #pragma unroll
        for (int kk = 0; kk < 2; ++kk) {
            int o = ob + j * 16 + lm;
            fw[j][kk] = *(const short8*)(pwb + (size_t)o * CCH + h * 64 +
                                         kk * 32 + quad * 8);
        }
    float4v acc[4][4];
    #pragma unroll
    for (int i = 0; i < 4; ++i)
        #pragma unroll
        for (int j = 0; j < 4; ++j) acc[i][j] = {0.f, 0.f, 0.f, 0.f};
    #pragma unroll
    for (int kk = 0; kk < 2; ++kk)
        #pragma unroll
        for (int i = 0; i < 4; ++i)
            #pragma unroll
            for (int j = 0; j < 4; ++j)
                acc[i][j] = __builtin_amdgcn_mfma_f32_16x16x32_bf16(
                    ka[i][kk], fw[j][kk], acc[i][j], 0, 0, 0);
    // rows=d (quad*4+r), cols=o (lm): store 4 consecutive c at row o.
    #pragma unroll
    for (int i = 0; i < 4; ++i)
        #pragma unroll
        for (int j = 0; j < 4; ++j) {
            int o = ob + j * 16 + lm;
            int c = h * 64 + i * 16 + quad * 4;
            ushort4v pk;
            #pragma unroll
            for (int r = 0; r < 4; ++r) pk[r] = f2bf(acc[i][j][r]);
            *(ushort4v*)(Mw + ((size_t)b * CCH + o) * CCH + c) = pk;
        }
}

// ---------------------------------------------------------------------------
// Kernel 5: proj GEMM on qT with per-batch folded weights M_b (BK=64 dbuf,
// XCD-swizzled).  out[n][o] = (sum_c q[n][c] M_b[o][c]) / den[n] + bias + resid
// den[n] computed in the K-loop from staged B fragments (shfl_xor reduce).
__global__ __launch_bounds__(256) void gemm_proj(const unsigned short* __restrict__ Mw,
                                                 const unsigned short* __restrict__ Bt,
                                                 const float* __restrict__ bias,
                                                 const float* __restrict__ ksum,
                                                 const float* __restrict__ resid,
                                                 float* __restrict__ outF) {
    // T1: dispatch id -> XCD-chunked work id; 128 % 8 == 0; o fastest.
    const int fid = blockIdx.y * 32 + blockIdx.x;       // 0..127
    const int w   = (fid & 7) * 16 + (fid >> 3);        // bijective remap
    const int o0  = (w & 3) * 128;
    const int n0  = (w >> 2) * 128;

    const int b  = blockIdx.z;
    const int t  = threadIdx.x;
    const int wv = t >> 6, ln = t & 63;
    const int quad = ln >> 4, lm = ln & 15;
    const int wo = (wv >> 1) * 64, wn = (wv & 1) * 64;

    __shared__ __align__(16) unsigned short sh[32768];

    float4v acc[4][4];
    #pragma unroll
    for (int i = 0; i < 4; ++i)
        #pragma unroll
        for (int j = 0; j < 4; ++j) acc[i][j] = {0.f, 0.f, 0.f, 0.f};
    float den4[4] = {0.f, 0.f, 0.f, 0.f};

    const unsigned short* aBase = Mw + ((size_t)b * CCH + o0) * CCH;
    const unsigned short* bBase = Bt + ((size_t)b * NSP + n0) * CCH;
    const float* kssB = ksum + b * CCH + quad * 8;

    const int srow8 = ln >> 3;
    const int scs   = ((ln & 7) ^ srow8) * 8;
    const int lmp   = lm & 7;

    #pragma unroll
    for (int i = 0; i < 4; ++i) {
        int slab = wv + i * 4;
        GLOAD_LDS16(aBase + (size_t)(slab * 8 + srow8) * CCH + scs,
                    sh + slab * 512);
        GLOAD_LDS16(bBase + (size_t)(slab * 8 + srow8) * CCH + scs,
                    sh + 8192 + slab * 512);
    }
    __syncthreads();

    int cur = 0;
    for (int step = 0; step < 8; ++step) {
        if (step < 7) {
            const int nb = (cur ^ 1) * 16384;
            const int k1 = (step + 1) * 64;
            #pragma unroll
            for (int i = 0; i < 4; ++i) {
                int slab = wv + i * 4;
                GLOAD_LDS16(aBase + (size_t)(slab * 8 + srow8) * CCH + k1 + scs,
                            sh + nb + slab * 512);
                GLOAD_LDS16(bBase + (size_t)(slab * 8 + srow8) * CCH + k1 + scs,
                            sh + nb + 8192 + slab * 512);
            }
        }
        const unsigned short* Ab = sh + cur * 16384;
        const unsigned short* Bb = Ab + 8192;
        #pragma unroll
        for (int kk = 0; kk < 2; ++kk) {
            const int sc8 = ((kk * 4 + quad) ^ lmp) * 8;
            short8 fw[4], fx[4];
            #pragma unroll
            for (int i = 0; i < 4; ++i)
                fw[i] = *(const short8*)(Ab + (wo + i * 16 + lm) * 64 + sc8);
            #pragma unroll
            for (int j = 0; j < 4; ++j)
                fx[j] = *(const short8*)(Bb + (wn + j * 16 + lm) * 64 + sc8);
            // den partials (logical k = step*64 + kk*32 + quad*8 + l)
            {
                float4 ka4 = *(const float4*)(kssB + step * 64 + kk * 32);
                float4 kb4 = *(const float4*)(kssB + step * 64 + kk * 32 + 4);
                float kf[8] = {ka4.x, ka4.y, ka4.z, ka4.w,
                               kb4.x, kb4.y, kb4.z, kb4.w};
                #pragma unroll
                for (int j = 0; j < 4; ++j)
                    #pragma unroll
                    for (int l = 0; l < 8; ++l)
                        den4[j] += bf2f((unsigned short)fx[j][l]) * kf[l];
            }
            #pragma unroll
            for (int i = 0; i < 4; ++i)
                #pragma unroll
                for (int j = 0; j < 4; ++j)
                    acc[i][j] = __builtin_amdgcn_mfma_f32_16x16x32_bf16(
                        fx[j], fw[i], acc[i][j], 0, 0, 0);
        }
        if (step < 7) __syncthreads();
        cur ^= 1;
    }

    // complete den: sum the 4 quad partials; every lane then holds den for
    // its lm row; epilogue rows n = wn+j*16+quad*4+r fetch lane quad*4+r.
    #pragma unroll
    for (int j = 0; j < 4; ++j) {
        den4[j] += __shfl_xor(den4[j], 16);
        den4[j] += __shfl_xor(den4[j], 32);
    }
    float4v rden[4];
    #pragma unroll
    for (int j = 0; j < 4; ++j)
        #pragma unroll
        for (int r = 0; r < 4; ++r)
            rden[j][r] = 1.f / (__shfl(den4[j], quad * 4 + r) + 1e-6f);

    // rows=n (quad*4+r), cols=o (lm). den-divide + bias + resid epilogue.
    #pragma unroll
    for (int i = 0; i < 4; ++i) {
        int o = o0 + wo + i * 16 + lm;
        float bs = bias[o];
        #pragma unroll
        for (int j = 0; j < 4; ++j) {
            int n = n0 + wn + j * 16 + quad * 4;
            size_t off = ((size_t)b * CCH + o) * NSP + n;
            float4 rv = *(const float4*)(resid + off);
            float4 w2 = {acc[i][j][0] * rden[j][0] + bs + rv.x,
                         acc[i][j][1] * rden[j][1] + bs + rv.y,
                         acc[i][j][2] * rden[j][2] + bs + rv.z,
                         acc[i][j][3] * rden[j][3] + bs + rv.w};
            *(float4*)(outF + off) = w2;
        }
    }
}

// ---------------------------------------------------------------------------
extern "C" void kernel_launch(void* const* d_in, const int* in_sizes, int n_in,
                              void* d_out, int out_size, void* d_ws, size_t ws_size,
                              hipStream_t stream) {
    const float* x      = (const float*)d_in[0];
    const float* gamma  = (const float*)d_in[1];
    const float* beta   = (const float*)d_in[2];
    const float* qkv_w  = (const float*)d_in[3];
    const float* qkv_b  = (const float*)d_in[4];
    const float* proj_w = (const float*)d_in[5];
    const float* proj_b = (const float*)d_in[6];
    float* out = (float*)d_out;

    // workspace layout (float units)
    float* ws   = (float*)d_ws;
    float* ss   = ws;                                   //    8192
    float* ksum = ss + 8192;                            //    4096
    float* kvp  = ksum + 4096;                          // 32*64*64*64
    unsigned short* xnT  = (unsigned short*)(kvp + (size_t)32 * 64 * 64 * 64);
    unsigned short* qT   = xnT + (size_t)BATCH * NSP * CCH;
    unsigned short* Mw   = qT  + (size_t)BATCH * NSP * CCH;
    unsigned short* wqb  = Mw + (size_t)BATCH * CCH * CCH;
    unsigned short* wpb  = wqb + (size_t)O1 * CCH;

    pre_kernel<<<1280, 256, 0, stream>>>(x, gamma, beta, qkv_w, proj_w,
                                         wqb, wpb, ksum, ss);
    xnT_kernel<<<dim3(NSP / 64, CCH / 64, BATCH), 256, 0, stream>>>(x, ss, xnT);

    gemm_qkv<<<dim3(NSP / 128, 12, BATCH), 256, 0, stream>>>(
        wqb, xnT, qkv_b, qT, ksum, kvp);

    post_kernel<<<128, 256, 0, stream>>>(kvp, wpb, Mw);

    gemm_proj<<<dim3(NSP / 128, CCH / 128, BATCH), 256, 0, stream>>>(
        Mw, qT, proj_b, ksum, x, out);
}